// Round 2
// baseline (286.541 us; speedup 1.0000x reference)
//
#include <hip/hip_runtime.h>
#include <hip/hip_bf16.h>
#include <cstddef>
#include <cstdint>

// Problem constants (fixed by the reference setup)
#define N_B   8
#define L_L   4096
#define S_S   4096
#define H_H   8
#define D_D   64
#define NH    64          // N_B * H_H
#define COLS  65          // Dv + 1 (col 64 = K_sum)
#define ROWSZ 4160        // COLS * 64, floats per (n,h) KV_aug matrix

__device__ __forceinline__ float elu1(float x) {
    // elu(x)+1 : x>0 ? x+1 : exp(x)
    return x > 0.f ? x + 1.f : __expf(x);
}

// ---------------------------------------------------------------------------
// Phase 1: per (n,h, s-chunk) block computes partial KV_aug[65][64]
//   KV[d][v] = sum_s Kf[s][d] * V[s][v],   row 64 = K_sum[d]
// 4 waves split the s-range; each lane owns an 8x8 register tile of the 64x64
// output. No atomics: cross-wave reduce in LDS, partial written to d_ws.
// ---------------------------------------------------------------------------
__global__ __launch_bounds__(256, 4)
void la_phase1(const float* __restrict__ Kin, const float* __restrict__ Vin,
               float* __restrict__ partials, int split, int schunk)
{
    __shared__ float sK[32 * 64];        // 8 KB
    __shared__ float sV[32 * 64];        // 8 KB
    __shared__ float sAcc[64 * 68];      // 17 KB, stride 68 to dodge conflicts
    __shared__ float sKsumP[4 * 64];     // per-wave ksum partials

    const int b     = blockIdx.x;
    const int nh    = b / split;
    const int chunk = b - nh * split;
    const int n     = nh >> 3;
    const int h     = nh & 7;
    const int s0    = chunk * schunk;

    const int tid  = threadIdx.x;
    const int w    = tid >> 6;
    const int lane = tid & 63;
    const int dg   = lane >> 3;   // d-group: d = dg*8 + i
    const int vg   = lane & 7;    // v-group: v = vg*8 + j

    float acc[8][8];
    #pragma unroll
    for (int i = 0; i < 8; ++i)
        #pragma unroll
        for (int j = 0; j < 8; ++j) acc[i][j] = 0.f;
    float ksum = 0.f;

    // staging map: 256 threads cover 32 rows x 64 cols, 8 floats each
    const int sr = tid >> 3;          // 0..31
    const int sc = (tid & 7) * 8;     // 0,8,...,56
    const int kd = lane;              // ksum d index (per-wave full coverage)

    const float* Kb = Kin + (size_t)n * S_S * (H_H * D_D) + h * D_D;
    const float* Vb = Vin + (size_t)n * S_S * (H_H * D_D) + h * D_D;

    const int ntiles = schunk >> 5;   // tiles of 32 s-rows
    for (int t = 0; t < ntiles; ++t) {
        const int srow = s0 + t * 32;
        {
            const float* kg = Kb + (size_t)(srow + sr) * (H_H * D_D) + sc;
            const float* vgp = Vb + (size_t)(srow + sr) * (H_H * D_D) + sc;
            float4 ka = *(const float4*)kg;
            float4 kb = *(const float4*)(kg + 4);
            float4 va = *(const float4*)vgp;
            float4 vb = *(const float4*)(vgp + 4);
            ka.x = elu1(ka.x); ka.y = elu1(ka.y); ka.z = elu1(ka.z); ka.w = elu1(ka.w);
            kb.x = elu1(kb.x); kb.y = elu1(kb.y); kb.z = elu1(kb.z); kb.w = elu1(kb.w);
            *(float4*)&sK[sr * 64 + sc]     = ka;
            *(float4*)&sK[sr * 64 + sc + 4] = kb;
            *(float4*)&sV[sr * 64 + sc]     = va;
            *(float4*)&sV[sr * 64 + sc + 4] = vb;
        }
        __syncthreads();

        // wave w handles s-local rows w*8 .. w*8+7
        #pragma unroll
        for (int sl = 0; sl < 8; ++sl) {
            const int s = w * 8 + sl;
            const float4 k0 = *(const float4*)&sK[s * 64 + dg * 8];
            const float4 k1 = *(const float4*)&sK[s * 64 + dg * 8 + 4];
            const float4 v0 = *(const float4*)&sV[s * 64 + vg * 8];
            const float4 v1 = *(const float4*)&sV[s * 64 + vg * 8 + 4];
            const float kf[8] = {k0.x, k0.y, k0.z, k0.w, k1.x, k1.y, k1.z, k1.w};
            const float vf[8] = {v0.x, v0.y, v0.z, v0.w, v1.x, v1.y, v1.z, v1.w};
            #pragma unroll
            for (int i = 0; i < 8; ++i)
                #pragma unroll
                for (int j = 0; j < 8; ++j)
                    acc[i][j] = fmaf(kf[i], vf[j], acc[i][j]);
        }
        // K_sum partial: each lane of wave w sums its column d=kd over the
        // same 8 rows this wave consumed (conflict-free: lanes hit distinct banks)
        #pragma unroll
        for (int sl = 0; sl < 8; ++sl)
            ksum += sK[(w * 8 + sl) * 64 + kd];
        __syncthreads();
    }

    // cross-wave reduce of acc into sAcc[d][v] (stride 68), sequential & exact
    for (int ww = 0; ww < 4; ++ww) {
        if (w == ww) {
            #pragma unroll
            for (int i = 0; i < 8; ++i) {
                float* p = &sAcc[(dg * 8 + i) * 68 + vg * 8];
                if (ww == 0) {
                    *(float4*)p       = make_float4(acc[i][0], acc[i][1], acc[i][2], acc[i][3]);
                    *(float4*)(p + 4) = make_float4(acc[i][4], acc[i][5], acc[i][6], acc[i][7]);
                } else {
                    float4 a0 = *(const float4*)p;
                    float4 a1 = *(const float4*)(p + 4);
                    a0.x += acc[i][0]; a0.y += acc[i][1]; a0.z += acc[i][2]; a0.w += acc[i][3];
                    a1.x += acc[i][4]; a1.y += acc[i][5]; a1.z += acc[i][6]; a1.w += acc[i][7];
                    *(float4*)p       = a0;
                    *(float4*)(p + 4) = a1;
                }
            }
        }
        __syncthreads();
    }

    // ksum: deterministic 4-way reduce (one slot per (wave, d))
    sKsumP[w * 64 + kd] = ksum;
    __syncthreads();

    // write this block's partial KV_aug in [v][d] layout (v=64 row = K_sum)
    float* outp = partials + (size_t)b * ROWSZ;
    for (int idx = tid; idx < ROWSZ; idx += 256) {
        const int v = idx >> 6;
        const int d = idx & 63;
        float val;
        if (v == 64)
            val = sKsumP[d] + sKsumP[64 + d] + sKsumP[128 + d] + sKsumP[192 + d];
        else
            val = sAcc[d * 68 + v];
        outp[idx] = val;
    }
}

// ---------------------------------------------------------------------------
// Reduce: sum the `split` partials per (n,h) -> kvt[nh][65][64]
// ---------------------------------------------------------------------------
__global__ __launch_bounds__(256)
void la_reduce(const float* __restrict__ partials, float* __restrict__ kvt, int split)
{
    const int idx = blockIdx.x * 256 + threadIdx.x;
    if (idx >= NH * ROWSZ) return;
    const int nh  = idx / ROWSZ;
    const int rem = idx - nh * ROWSZ;
    const float* p = partials + (size_t)nh * split * ROWSZ + rem;
    float s = 0.f;
    for (int c = 0; c < split; ++c) s += p[(size_t)c * ROWSZ];
    kvt[idx] = s;
}

// ---------------------------------------------------------------------------
// Phase 2: thread-per-row.  out[l][v] = (Qf[l] . KV[:,v]) / (Qf[l].K_sum + eps)
// KV_aug staged in LDS; all inner reads are wave-uniform (free broadcast).
// ---------------------------------------------------------------------------
__global__ __launch_bounds__(256, 4)
void la_phase2(const float* __restrict__ Qin, const float* __restrict__ kvt,
               float* __restrict__ Out)
{
    __shared__ float sKV[ROWSZ];   // 16.6 KB

    const int b  = blockIdx.x;
    const int nh = b >> 4;         // L/256 = 16 chunks per (n,h)
    const int lc = b & 15;
    const int n  = nh >> 3;
    const int h  = nh & 7;
    const int tid = threadIdx.x;

    const float* kvsrc = kvt + (size_t)nh * ROWSZ;
    for (int idx = tid; idx < ROWSZ; idx += 256) sKV[idx] = kvsrc[idx];
    __syncthreads();

    const int l = lc * 256 + tid;
    const float* qp = Qin + (((size_t)n * L_L + l) * H_H + h) * D_D;

    float q[64];
    #pragma unroll
    for (int d4 = 0; d4 < 16; ++d4) {
        const float4 qq = *(const float4*)(qp + d4 * 4);
        q[d4 * 4 + 0] = elu1(qq.x);
        q[d4 * 4 + 1] = elu1(qq.y);
        q[d4 * 4 + 2] = elu1(qq.z);
        q[d4 * 4 + 3] = elu1(qq.w);
    }

    const float4* kv4 = (const float4*)sKV;

    // denominator: row v=64 (K_sum)
    float den = 0.f;
    #pragma unroll
    for (int d4 = 0; d4 < 16; ++d4) {
        const float4 kk = kv4[64 * 16 + d4];
        den += q[d4 * 4 + 0] * kk.x + q[d4 * 4 + 1] * kk.y
             + q[d4 * 4 + 2] * kk.z + q[d4 * 4 + 3] * kk.w;
    }
    const float rz = 1.0f / (den + 1e-6f);

    float* op = Out + (((size_t)n * L_L + l) * H_H + h) * D_D;

    for (int vb = 0; vb < 16; ++vb) {
        float a0 = 0.f, a1 = 0.f, a2 = 0.f, a3 = 0.f;
        #pragma unroll 2
        for (int d4 = 0; d4 < 16; ++d4) {
            const float4 c0 = kv4[(vb * 4 + 0) * 16 + d4];
            const float4 c1 = kv4[(vb * 4 + 1) * 16 + d4];
            const float4 c2 = kv4[(vb * 4 + 2) * 16 + d4];
            const float4 c3 = kv4[(vb * 4 + 3) * 16 + d4];
            const float q0 = q[d4 * 4 + 0], q1 = q[d4 * 4 + 1];
            const float q2 = q[d4 * 4 + 2], q3 = q[d4 * 4 + 3];
            a0 = fmaf(q0, c0.x, a0); a0 = fmaf(q1, c0.y, a0);
            a0 = fmaf(q2, c0.z, a0); a0 = fmaf(q3, c0.w, a0);
            a1 = fmaf(q0, c1.x, a1); a1 = fmaf(q1, c1.y, a1);
            a1 = fmaf(q2, c1.z, a1); a1 = fmaf(q3, c1.w, a1);
            a2 = fmaf(q0, c2.x, a2); a2 = fmaf(q1, c2.y, a2);
            a2 = fmaf(q2, c2.z, a2); a2 = fmaf(q3, c2.w, a2);
            a3 = fmaf(q0, c3.x, a3); a3 = fmaf(q1, c3.y, a3);
            a3 = fmaf(q2, c3.z, a3); a3 = fmaf(q3, c3.w, a3);
        }
        *(float4*)(op + vb * 4) = make_float4(a0 * rz, a1 * rz, a2 * rz, a3 * rz);
    }
}

// ---------------------------------------------------------------------------
extern "C" void kernel_launch(void* const* d_in, const int* in_sizes, int n_in,
                              void* d_out, int out_size, void* d_ws, size_t ws_size,
                              hipStream_t stream)
{
    const float* Q = (const float*)d_in[0];
    const float* K = (const float*)d_in[1];
    const float* V = (const float*)d_in[2];
    float* out = (float*)d_out;

    // ws layout: [ kvt: NH*ROWSZ floats ][ partials: NH*split*ROWSZ floats ]
    float* kvt = (float*)d_ws;
    const size_t kvt_bytes = (size_t)NH * ROWSZ * sizeof(float);

    int split = 16;
    while (split > 1 &&
           kvt_bytes + (size_t)NH * split * ROWSZ * sizeof(float) > ws_size)
        split >>= 1;
    float* partials = kvt + (size_t)NH * ROWSZ;
    const int schunk = S_S / split;

    la_phase1<<<NH * split, 256, 0, stream>>>(K, V, partials, split, schunk);

    const int red_blocks = (NH * ROWSZ + 255) / 256;   // 1040 exactly
    la_reduce<<<red_blocks, 256, 0, stream>>>(partials, kvt, split);

    la_phase2<<<NH * (L_L / 256), 256, 0, stream>>>(Q, kvt, out);
}

// Round 3
// 186.310 us; speedup vs baseline: 1.5380x; 1.5380x over previous
//
#include <hip/hip_runtime.h>
#include <hip/hip_bf16.h>
#include <cstddef>
#include <cstdint>

// Problem constants (fixed by the reference setup)
#define N_B   8
#define L_L   4096
#define S_S   4096
#define H_H   8
#define D_D   64
#define NH    64          // N_B * H_H
#define COLS  65          // Dv + 1 (col 64 = K_sum)
#define ROWSZ 4160        // COLS * 64, floats per (n,h) KV_aug matrix

__device__ __forceinline__ float elu1(float x) {
    // elu(x)+1 : x>0 ? x+1 : exp(x)
    return x > 0.f ? x + 1.f : __expf(x);
}

// ---------------------------------------------------------------------------
// Phase 1: per (n,h, s-chunk) block computes partial KV_aug[65][64]
//   KV[d][v] = sum_s Kf[s][d] * V[s][v],   row 64 = K_sum[d]
// 4 waves split the s-range; each lane owns an 8x8 register tile of the 64x64
// output. No atomics: cross-wave reduce in LDS, partial written to d_ws.
// ---------------------------------------------------------------------------
__global__ __launch_bounds__(256, 4)
void la_phase1(const float* __restrict__ Kin, const float* __restrict__ Vin,
               float* __restrict__ partials, int split, int schunk)
{
    __shared__ float sK[32 * 64];        // 8 KB
    __shared__ float sV[32 * 64];        // 8 KB
    __shared__ float sAcc[64 * 68];      // 17 KB, stride 68 to dodge conflicts
    __shared__ float sKsumP[4 * 64];     // per-wave ksum partials

    const int b     = blockIdx.x;
    const int nh    = b / split;
    const int chunk = b - nh * split;
    const int n     = nh >> 3;
    const int h     = nh & 7;
    const int s0    = chunk * schunk;

    const int tid  = threadIdx.x;
    const int w    = tid >> 6;
    const int lane = tid & 63;
    const int dg   = lane >> 3;   // d-group: d = dg*8 + i
    const int vg   = lane & 7;    // v-group: v = vg*8 + j

    float acc[8][8];
    #pragma unroll
    for (int i = 0; i < 8; ++i)
        #pragma unroll
        for (int j = 0; j < 8; ++j) acc[i][j] = 0.f;
    float ksum = 0.f;

    // staging map: 256 threads cover 32 rows x 64 cols, 8 floats each
    const int sr = tid >> 3;          // 0..31
    const int sc = (tid & 7) * 8;     // 0,8,...,56
    const int kd = lane;              // ksum d index (per-wave full coverage)

    const float* Kb = Kin + (size_t)n * S_S * (H_H * D_D) + h * D_D;
    const float* Vb = Vin + (size_t)n * S_S * (H_H * D_D) + h * D_D;

    const int ntiles = schunk >> 5;   // tiles of 32 s-rows
    for (int t = 0; t < ntiles; ++t) {
        const int srow = s0 + t * 32;
        {
            const float* kg = Kb + (size_t)(srow + sr) * (H_H * D_D) + sc;
            const float* vgp = Vb + (size_t)(srow + sr) * (H_H * D_D) + sc;
            float4 ka = *(const float4*)kg;
            float4 kb = *(const float4*)(kg + 4);
            float4 va = *(const float4*)vgp;
            float4 vb = *(const float4*)(vgp + 4);
            ka.x = elu1(ka.x); ka.y = elu1(ka.y); ka.z = elu1(ka.z); ka.w = elu1(ka.w);
            kb.x = elu1(kb.x); kb.y = elu1(kb.y); kb.z = elu1(kb.z); kb.w = elu1(kb.w);
            *(float4*)&sK[sr * 64 + sc]     = ka;
            *(float4*)&sK[sr * 64 + sc + 4] = kb;
            *(float4*)&sV[sr * 64 + sc]     = va;
            *(float4*)&sV[sr * 64 + sc + 4] = vb;
        }
        __syncthreads();

        // wave w handles s-local rows w*8 .. w*8+7
        #pragma unroll
        for (int sl = 0; sl < 8; ++sl) {
            const int s = w * 8 + sl;
            const float4 k0 = *(const float4*)&sK[s * 64 + dg * 8];
            const float4 k1 = *(const float4*)&sK[s * 64 + dg * 8 + 4];
            const float4 v0 = *(const float4*)&sV[s * 64 + vg * 8];
            const float4 v1 = *(const float4*)&sV[s * 64 + vg * 8 + 4];
            const float kf[8] = {k0.x, k0.y, k0.z, k0.w, k1.x, k1.y, k1.z, k1.w};
            const float vf[8] = {v0.x, v0.y, v0.z, v0.w, v1.x, v1.y, v1.z, v1.w};
            #pragma unroll
            for (int i = 0; i < 8; ++i)
                #pragma unroll
                for (int j = 0; j < 8; ++j)
                    acc[i][j] = fmaf(kf[i], vf[j], acc[i][j]);
        }
        // K_sum partial over the same 8 rows this wave consumed
        #pragma unroll
        for (int sl = 0; sl < 8; ++sl)
            ksum += sK[(w * 8 + sl) * 64 + kd];
        __syncthreads();
    }

    // cross-wave reduce of acc into sAcc[d][v] (stride 68), sequential & exact
    for (int ww = 0; ww < 4; ++ww) {
        if (w == ww) {
            #pragma unroll
            for (int i = 0; i < 8; ++i) {
                float* p = &sAcc[(dg * 8 + i) * 68 + vg * 8];
                if (ww == 0) {
                    *(float4*)p       = make_float4(acc[i][0], acc[i][1], acc[i][2], acc[i][3]);
                    *(float4*)(p + 4) = make_float4(acc[i][4], acc[i][5], acc[i][6], acc[i][7]);
                } else {
                    float4 a0 = *(const float4*)p;
                    float4 a1 = *(const float4*)(p + 4);
                    a0.x += acc[i][0]; a0.y += acc[i][1]; a0.z += acc[i][2]; a0.w += acc[i][3];
                    a1.x += acc[i][4]; a1.y += acc[i][5]; a1.z += acc[i][6]; a1.w += acc[i][7];
                    *(float4*)p       = a0;
                    *(float4*)(p + 4) = a1;
                }
            }
        }
        __syncthreads();
    }

    // ksum: deterministic 4-way reduce (one slot per (wave, d))
    sKsumP[w * 64 + kd] = ksum;
    __syncthreads();

    // write this block's partial KV_aug in [v][d] layout (v=64 row = K_sum)
    float* outp = partials + (size_t)b * ROWSZ;
    for (int idx = tid; idx < ROWSZ; idx += 256) {
        const int v = idx >> 6;
        const int d = idx & 63;
        float val;
        if (v == 64)
            val = sKsumP[d] + sKsumP[64 + d] + sKsumP[128 + d] + sKsumP[192 + d];
        else
            val = sAcc[d * 68 + v];
        outp[idx] = val;
    }
}

// ---------------------------------------------------------------------------
// Reduce: sum the `split` partials per (n,h) -> kvt[nh][65][64]
// ---------------------------------------------------------------------------
__global__ __launch_bounds__(256)
void la_reduce(const float* __restrict__ partials, float* __restrict__ kvt, int split)
{
    const int idx = blockIdx.x * 256 + threadIdx.x;
    if (idx >= NH * ROWSZ) return;
    const int nh  = idx / ROWSZ;
    const int rem = idx - nh * ROWSZ;
    const float* p = partials + (size_t)nh * split * ROWSZ + rem;
    float s = 0.f;
    for (int c = 0; c < split; ++c) s += p[(size_t)c * ROWSZ];
    kvt[idx] = s;
}

// ---------------------------------------------------------------------------
// Phase 2 (v2): thread-per-row, 256 rows/block for fixed (n,h).
//  - Q staged via LDS in two 128-row half-tiles (stride 68): global reads are
//    per-instruction fully coalesced (16 lanes cover one row's 256B).
//  - q[64] kept ENTIRELY in VGPRs: every loop touching q is fully unrolled
//    (the old partial unroll demoted q to scratch -> VGPR_Count=64, ~1GB
//    of hidden scratch traffic).
//  - KV_aug read directly from global with wave-uniform indices (one request
//    per wave, L1/L2-resident; 16.6KB per (n,h)).
//  - Output staged through the same LDS buffer (256 rows x 32 floats,
//    stride 36), flushed twice with fully-coalesced 128B-per-row stores.
// ---------------------------------------------------------------------------
__global__ __launch_bounds__(256, 4)
void la_phase2(const float* __restrict__ Qin, const float* __restrict__ kvt,
               float* __restrict__ Out)
{
    __shared__ float sbuf[256 * 36];   // 36.9 KB: q half-tiles, then out-tile

    const int b   = blockIdx.x;
    const int nh  = b >> 4;            // 16 l-chunks per (n,h)
    const int lc  = b & 15;
    const int n   = nh >> 3;
    const int h   = nh & 7;
    const int tid = threadIdx.x;

    const float* Qc = Qin + (((size_t)n * L_L + (size_t)lc * 256) * H_H + h) * D_D;
    float*       Oc = Out + (((size_t)n * L_L + (size_t)lc * 256) * H_H + h) * D_D;

    float q[64];

    // ---- stage Q in two 128-row half-tiles ----
    for (int hf = 0; hf < 2; ++hf) {
        __syncthreads();   // protect buffer from previous half's readback
        #pragma unroll
        for (int it = 0; it < 8; ++it) {
            const int slot = it * 256 + tid;     // 0..2047
            const int r    = slot >> 4;          // 0..127
            const int c4   = slot & 15;
            float4 v = *(const float4*)(Qc + (size_t)(hf * 128 + r) * (H_H * D_D) + c4 * 4);
            v.x = elu1(v.x); v.y = elu1(v.y); v.z = elu1(v.z); v.w = elu1(v.w);
            *(float4*)&sbuf[r * 68 + c4 * 4] = v;
        }
        __syncthreads();
        if ((tid >> 7) == hf) {
            const int r = tid & 127;
            #pragma unroll
            for (int j = 0; j < 16; ++j) {
                const float4 v = *(const float4*)&sbuf[r * 68 + j * 4];
                q[j * 4 + 0] = v.x; q[j * 4 + 1] = v.y;
                q[j * 4 + 2] = v.z; q[j * 4 + 3] = v.w;
            }
        }
    }
    __syncthreads();   // all readbacks done; buffer now free for out-tile

    // ---- wave-uniform KV reads from global ----
    const float4* __restrict__ kvp = (const float4*)(kvt + (size_t)nh * ROWSZ);

    // denominator: row v=64 of KV_aug is K_sum
    float den = 0.f;
    #pragma unroll
    for (int d4 = 0; d4 < 16; ++d4) {
        const float4 kk = kvp[64 * 16 + d4];
        den = fmaf(q[d4 * 4 + 0], kk.x, den);
        den = fmaf(q[d4 * 4 + 1], kk.y, den);
        den = fmaf(q[d4 * 4 + 2], kk.z, den);
        den = fmaf(q[d4 * 4 + 3], kk.w, den);
    }
    const float rz = 1.0f / (den + 1e-6f);

    // ---- main loop: vb dynamic, d4 FULLY unrolled (q stays in VGPRs) ----
    for (int vb = 0; vb < 16; ++vb) {
        float a0 = 0.f, a1 = 0.f, a2 = 0.f, a3 = 0.f;
        #pragma unroll
        for (int d4 = 0; d4 < 16; ++d4) {
            const float4 c0 = kvp[(vb * 4 + 0) * 16 + d4];
            const float4 c1 = kvp[(vb * 4 + 1) * 16 + d4];
            const float4 c2 = kvp[(vb * 4 + 2) * 16 + d4];
            const float4 c3 = kvp[(vb * 4 + 3) * 16 + d4];
            const float q0 = q[d4 * 4 + 0], q1 = q[d4 * 4 + 1];
            const float q2 = q[d4 * 4 + 2], q3 = q[d4 * 4 + 3];
            a0 = fmaf(q0, c0.x, a0); a0 = fmaf(q1, c0.y, a0);
            a0 = fmaf(q2, c0.z, a0); a0 = fmaf(q3, c0.w, a0);
            a1 = fmaf(q0, c1.x, a1); a1 = fmaf(q1, c1.y, a1);
            a1 = fmaf(q2, c1.z, a1); a1 = fmaf(q3, c1.w, a1);
            a2 = fmaf(q0, c2.x, a2); a2 = fmaf(q1, c2.y, a2);
            a2 = fmaf(q2, c2.z, a2); a2 = fmaf(q3, c2.w, a2);
            a3 = fmaf(q0, c3.x, a3); a3 = fmaf(q1, c3.y, a3);
            a3 = fmaf(q2, c3.z, a3); a3 = fmaf(q3, c3.w, a3);
        }
        // stash this row's 4 outputs in the out-tile (row = tid, stride 36)
        *(float4*)&sbuf[tid * 36 + (vb & 7) * 4] =
            make_float4(a0 * rz, a1 * rz, a2 * rz, a3 * rz);

        if ((vb & 7) == 7) {           // flush half the v-range, coalesced
            __syncthreads();
            const int vh = vb >> 3;    // 0 or 1
            #pragma unroll
            for (int it = 0; it < 8; ++it) {
                const int slot = it * 256 + tid;   // 0..2047
                const int r    = slot >> 3;        // 0..255
                const int c8   = slot & 7;
                const float4 v = *(const float4*)&sbuf[r * 36 + c8 * 4];
                *(float4*)(Oc + (size_t)r * (H_H * D_D) + vh * 32 + c8 * 4) = v;
            }
            __syncthreads();
        }
    }
}

// ---------------------------------------------------------------------------
extern "C" void kernel_launch(void* const* d_in, const int* in_sizes, int n_in,
                              void* d_out, int out_size, void* d_ws, size_t ws_size,
                              hipStream_t stream)
{
    const float* Q = (const float*)d_in[0];
    const float* K = (const float*)d_in[1];
    const float* V = (const float*)d_in[2];
    float* out = (float*)d_out;

    // ws layout: [ kvt: NH*ROWSZ floats ][ partials: NH*split*ROWSZ floats ]
    float* kvt = (float*)d_ws;
    const size_t kvt_bytes = (size_t)NH * ROWSZ * sizeof(float);

    int split = 16;
    while (split > 1 &&
           kvt_bytes + (size_t)NH * split * ROWSZ * sizeof(float) > ws_size)
        split >>= 1;
    float* partials = kvt + (size_t)NH * ROWSZ;
    const int schunk = S_S / split;

    la_phase1<<<NH * split, 256, 0, stream>>>(K, V, partials, split, schunk);

    const int red_blocks = (NH * ROWSZ + 255) / 256;   // 1040 exactly
    la_reduce<<<red_blocks, 256, 0, stream>>>(partials, kvt, split);

    la_phase2<<<NH * (L_L / 256), 256, 0, stream>>>(Q, kvt, out);
}

// Round 4
// 149.616 us; speedup vs baseline: 1.9152x; 1.2453x over previous
//
#include <hip/hip_runtime.h>
#include <hip/hip_bf16.h>
#include <cstddef>
#include <cstdint>

// Problem constants (fixed by the reference setup)
#define N_B   8
#define L_L   4096
#define S_S   4096
#define H_H   8
#define D_D   64
#define NH    64          // N_B * H_H
#define COLS  65          // Dv + 1 (col 64 = K_sum)
#define ROWSZ 4160        // COLS * 64, floats per (n,h) KV_aug matrix

__device__ __forceinline__ float elu1(float x) {
    // elu(x)+1 : x>0 ? x+1 : exp(x)
    return x > 0.f ? x + 1.f : __expf(x);
}

// ---------------------------------------------------------------------------
// Phase 1: per (n,h, s-chunk) block computes partial KV_aug[65][64]
//   KV[d][v] = sum_s Kf[s][d] * V[s][v],   row 64 = K_sum[d]
// 4 waves split the s-range; each lane owns an 8x8 register tile of the 64x64
// output. No atomics: cross-wave reduce in LDS, partial written to d_ws.
// ---------------------------------------------------------------------------
__global__ __launch_bounds__(256, 4)
void la_phase1(const float* __restrict__ Kin, const float* __restrict__ Vin,
               float* __restrict__ partials, int split, int schunk)
{
    __shared__ float sK[32 * 64];        // 8 KB
    __shared__ float sV[32 * 64];        // 8 KB
    __shared__ float sAcc[64 * 68];      // 17 KB, stride 68 to dodge conflicts
    __shared__ float sKsumP[4 * 64];     // per-wave ksum partials

    const int b     = blockIdx.x;
    const int nh    = b / split;
    const int chunk = b - nh * split;
    const int n     = nh >> 3;
    const int h     = nh & 7;
    const int s0    = chunk * schunk;

    const int tid  = threadIdx.x;
    const int w    = tid >> 6;
    const int lane = tid & 63;
    const int dg   = lane >> 3;   // d-group: d = dg*8 + i
    const int vg   = lane & 7;    // v-group: v = vg*8 + j

    float acc[8][8];
    #pragma unroll
    for (int i = 0; i < 8; ++i)
        #pragma unroll
        for (int j = 0; j < 8; ++j) acc[i][j] = 0.f;
    float ksum = 0.f;

    // staging map: 256 threads cover 32 rows x 64 cols, 8 floats each
    const int sr = tid >> 3;          // 0..31
    const int sc = (tid & 7) * 8;     // 0,8,...,56
    const int kd = lane;              // ksum d index (per-wave full coverage)

    const float* Kb = Kin + (size_t)n * S_S * (H_H * D_D) + h * D_D;
    const float* Vb = Vin + (size_t)n * S_S * (H_H * D_D) + h * D_D;

    const int ntiles = schunk >> 5;   // tiles of 32 s-rows
    for (int t = 0; t < ntiles; ++t) {
        const int srow = s0 + t * 32;
        {
            const float* kg = Kb + (size_t)(srow + sr) * (H_H * D_D) + sc;
            const float* vgp = Vb + (size_t)(srow + sr) * (H_H * D_D) + sc;
            float4 ka = *(const float4*)kg;
            float4 kb = *(const float4*)(kg + 4);
            float4 va = *(const float4*)vgp;
            float4 vb = *(const float4*)(vgp + 4);
            ka.x = elu1(ka.x); ka.y = elu1(ka.y); ka.z = elu1(ka.z); ka.w = elu1(ka.w);
            kb.x = elu1(kb.x); kb.y = elu1(kb.y); kb.z = elu1(kb.z); kb.w = elu1(kb.w);
            *(float4*)&sK[sr * 64 + sc]     = ka;
            *(float4*)&sK[sr * 64 + sc + 4] = kb;
            *(float4*)&sV[sr * 64 + sc]     = va;
            *(float4*)&sV[sr * 64 + sc + 4] = vb;
        }
        __syncthreads();

        // wave w handles s-local rows w*8 .. w*8+7
        #pragma unroll
        for (int sl = 0; sl < 8; ++sl) {
            const int s = w * 8 + sl;
            const float4 k0 = *(const float4*)&sK[s * 64 + dg * 8];
            const float4 k1 = *(const float4*)&sK[s * 64 + dg * 8 + 4];
            const float4 v0 = *(const float4*)&sV[s * 64 + vg * 8];
            const float4 v1 = *(const float4*)&sV[s * 64 + vg * 8 + 4];
            const float kf[8] = {k0.x, k0.y, k0.z, k0.w, k1.x, k1.y, k1.z, k1.w};
            const float vf[8] = {v0.x, v0.y, v0.z, v0.w, v1.x, v1.y, v1.z, v1.w};
            #pragma unroll
            for (int i = 0; i < 8; ++i)
                #pragma unroll
                for (int j = 0; j < 8; ++j)
                    acc[i][j] = fmaf(kf[i], vf[j], acc[i][j]);
        }
        // K_sum partial over the same 8 rows this wave consumed
        #pragma unroll
        for (int sl = 0; sl < 8; ++sl)
            ksum += sK[(w * 8 + sl) * 64 + kd];
        __syncthreads();
    }

    // cross-wave reduce of acc into sAcc[d][v] (stride 68), sequential & exact
    for (int ww = 0; ww < 4; ++ww) {
        if (w == ww) {
            #pragma unroll
            for (int i = 0; i < 8; ++i) {
                float* p = &sAcc[(dg * 8 + i) * 68 + vg * 8];
                if (ww == 0) {
                    *(float4*)p       = make_float4(acc[i][0], acc[i][1], acc[i][2], acc[i][3]);
                    *(float4*)(p + 4) = make_float4(acc[i][4], acc[i][5], acc[i][6], acc[i][7]);
                } else {
                    float4 a0 = *(const float4*)p;
                    float4 a1 = *(const float4*)(p + 4);
                    a0.x += acc[i][0]; a0.y += acc[i][1]; a0.z += acc[i][2]; a0.w += acc[i][3];
                    a1.x += acc[i][4]; a1.y += acc[i][5]; a1.z += acc[i][6]; a1.w += acc[i][7];
                    *(float4*)p       = a0;
                    *(float4*)(p + 4) = a1;
                }
            }
        }
        __syncthreads();
    }

    // ksum: deterministic 4-way reduce (one slot per (wave, d))
    sKsumP[w * 64 + kd] = ksum;
    __syncthreads();

    // write this block's partial KV_aug in [v][d] layout (v=64 row = K_sum)
    float* outp = partials + (size_t)b * ROWSZ;
    for (int idx = tid; idx < ROWSZ; idx += 256) {
        const int v = idx >> 6;
        const int d = idx & 63;
        float val;
        if (v == 64)
            val = sKsumP[d] + sKsumP[64 + d] + sKsumP[128 + d] + sKsumP[192 + d];
        else
            val = sAcc[d * 68 + v];
        outp[idx] = val;
    }
}

// ---------------------------------------------------------------------------
// Reduce: sum the `split` partials per (n,h) -> kvt[nh][65][64]
// ---------------------------------------------------------------------------
__global__ __launch_bounds__(256)
void la_reduce(const float* __restrict__ partials, float* __restrict__ kvt, int split)
{
    const int idx = blockIdx.x * 256 + threadIdx.x;
    if (idx >= NH * ROWSZ) return;
    const int nh  = idx / ROWSZ;
    const int rem = idx - nh * ROWSZ;
    const float* p = partials + (size_t)nh * split * ROWSZ + rem;
    float s = 0.f;
    for (int c = 0; c < split; ++c) s += p[(size_t)c * ROWSZ];
    kvt[idx] = s;
}

// ---------------------------------------------------------------------------
// Phase 2 (v3): thread-per-row, 256 rows/block for fixed (n,h).
//  Fixes vs v2 (which still spilled q[] -> VGPR_Count=64, 250MB scratch
//  fetch, 262K LDS bank conflicts):
//  - Staging halves MANUALLY unrolled, readback under static complementary
//    branches -> q[64] trivially mem2reg-promotable.
//  - __launch_bounds__(256,2): allocator cap 256 VGPR, needs ~120, no spill.
//  - XOR-swizzled LDS (float4 col ^= row&7): stride-64 Q tile and stride-32
//    out-tile are conflict-free for both ds_write_b128 and ds_read_b128.
//  - One reused 32KB buffer (Q half-tile, then out-tile halves).
//  - KV_aug read from global with wave-uniform addresses (L2-resident 1MB).
// ---------------------------------------------------------------------------
__global__ __launch_bounds__(256, 2)
void la_phase2(const float* __restrict__ Qin, const float* __restrict__ kvt,
               float* __restrict__ Out)
{
    __shared__ float sbuf[128 * 64];   // 32 KB, reused

    const int b   = blockIdx.x;
    const int nh  = b >> 4;            // 16 l-chunks per (n,h)
    const int lc  = b & 15;
    const int n   = nh >> 3;
    const int h   = nh & 7;
    const int tid = threadIdx.x;

    const float* Qc = Qin + (((size_t)n * L_L + (size_t)lc * 256) * H_H + h) * D_D;
    float*       Oc = Out + (((size_t)n * L_L + (size_t)lc * 256) * H_H + h) * D_D;

    // staging map: slot covers 128 rows x 16 float4
    const int strow = tid >> 4;        // +it*16
    const int stc4  = tid & 15;

    float q[64];

    // ---- half 0: rows 0..127 ----
    #pragma unroll
    for (int it = 0; it < 8; ++it) {
        const int r  = it * 16 + strow;
        const int c4 = stc4 ^ (r & 7);          // XOR swizzle (float4 units)
        float4 v = *(const float4*)(Qc + (size_t)r * (H_H * D_D) + stc4 * 4);
        v.x = elu1(v.x); v.y = elu1(v.y); v.z = elu1(v.z); v.w = elu1(v.w);
        *(float4*)&sbuf[r * 64 + c4 * 4] = v;
    }
    __syncthreads();
    if (tid < 128) {
        const int r = tid;
        #pragma unroll
        for (int j = 0; j < 16; ++j) {
            const float4 v = *(const float4*)&sbuf[r * 64 + (j ^ (r & 7)) * 4];
            q[j * 4 + 0] = v.x; q[j * 4 + 1] = v.y;
            q[j * 4 + 2] = v.z; q[j * 4 + 3] = v.w;
        }
    }
    __syncthreads();

    // ---- half 1: rows 128..255 ----
    #pragma unroll
    for (int it = 0; it < 8; ++it) {
        const int r  = it * 16 + strow;
        const int c4 = stc4 ^ (r & 7);
        float4 v = *(const float4*)(Qc + (size_t)(128 + r) * (H_H * D_D) + stc4 * 4);
        v.x = elu1(v.x); v.y = elu1(v.y); v.z = elu1(v.z); v.w = elu1(v.w);
        *(float4*)&sbuf[r * 64 + c4 * 4] = v;
    }
    __syncthreads();
    if (tid >= 128) {
        const int r = tid - 128;
        #pragma unroll
        for (int j = 0; j < 16; ++j) {
            const float4 v = *(const float4*)&sbuf[r * 64 + (j ^ (r & 7)) * 4];
            q[j * 4 + 0] = v.x; q[j * 4 + 1] = v.y;
            q[j * 4 + 2] = v.z; q[j * 4 + 3] = v.w;
        }
    }
    __syncthreads();   // buffer now free for out-tile

    // ---- wave-uniform KV reads from global ----
    const float4* __restrict__ kvp = (const float4*)(kvt + (size_t)nh * ROWSZ);

    // denominator: row v=64 of KV_aug is K_sum
    float den = 0.f;
    #pragma unroll
    for (int d4 = 0; d4 < 16; ++d4) {
        const float4 kk = kvp[64 * 16 + d4];
        den = fmaf(q[d4 * 4 + 0], kk.x, den);
        den = fmaf(q[d4 * 4 + 1], kk.y, den);
        den = fmaf(q[d4 * 4 + 2], kk.z, den);
        den = fmaf(q[d4 * 4 + 3], kk.w, den);
    }
    const float rz = 1.0f / (den + 1e-6f);

    // ---- main loop: vb dynamic, d4 FULLY unrolled (q stays in VGPRs) ----
    for (int vb = 0; vb < 16; ++vb) {
        float a0 = 0.f, a1 = 0.f, a2 = 0.f, a3 = 0.f;
        #pragma unroll
        for (int d4 = 0; d4 < 16; ++d4) {
            const float4 c0 = kvp[(vb * 4 + 0) * 16 + d4];
            const float4 c1 = kvp[(vb * 4 + 1) * 16 + d4];
            const float4 c2 = kvp[(vb * 4 + 2) * 16 + d4];
            const float4 c3 = kvp[(vb * 4 + 3) * 16 + d4];
            const float q0 = q[d4 * 4 + 0], q1 = q[d4 * 4 + 1];
            const float q2 = q[d4 * 4 + 2], q3 = q[d4 * 4 + 3];
            a0 = fmaf(q0, c0.x, a0); a0 = fmaf(q1, c0.y, a0);
            a0 = fmaf(q2, c0.z, a0); a0 = fmaf(q3, c0.w, a0);
            a1 = fmaf(q0, c1.x, a1); a1 = fmaf(q1, c1.y, a1);
            a1 = fmaf(q2, c1.z, a1); a1 = fmaf(q3, c1.w, a1);
            a2 = fmaf(q0, c2.x, a2); a2 = fmaf(q1, c2.y, a2);
            a2 = fmaf(q2, c2.z, a2); a2 = fmaf(q3, c2.w, a2);
            a3 = fmaf(q0, c3.x, a3); a3 = fmaf(q1, c3.y, a3);
            a3 = fmaf(q2, c3.z, a3); a3 = fmaf(q3, c3.w, a3);
        }
        // out-tile: row = tid (stride 32), XOR-swizzled float4 col
        *(float4*)&sbuf[tid * 32 + (((vb & 7)) ^ (tid & 7)) * 4] =
            make_float4(a0 * rz, a1 * rz, a2 * rz, a3 * rz);

        if ((vb & 7) == 7) {           // flush half the v-range, coalesced
            __syncthreads();
            const int vh = vb >> 3;    // 0 or 1
            #pragma unroll
            for (int it = 0; it < 8; ++it) {
                const int slot = it * 256 + tid;   // 0..2047
                const int r    = slot >> 3;        // 0..255
                const int c8   = slot & 7;
                const float4 v = *(const float4*)&sbuf[r * 32 + (c8 ^ (r & 7)) * 4];
                *(float4*)(Oc + (size_t)r * (H_H * D_D) + vh * 32 + c8 * 4) = v;
            }
            __syncthreads();
        }
    }
}

// ---------------------------------------------------------------------------
extern "C" void kernel_launch(void* const* d_in, const int* in_sizes, int n_in,
                              void* d_out, int out_size, void* d_ws, size_t ws_size,
                              hipStream_t stream)
{
    const float* Q = (const float*)d_in[0];
    const float* K = (const float*)d_in[1];
    const float* V = (const float*)d_in[2];
    float* out = (float*)d_out;

    // ws layout: [ kvt: NH*ROWSZ floats ][ partials: NH*split*ROWSZ floats ]
    float* kvt = (float*)d_ws;
    const size_t kvt_bytes = (size_t)NH * ROWSZ * sizeof(float);

    int split = 16;
    while (split > 1 &&
           kvt_bytes + (size_t)NH * split * ROWSZ * sizeof(float) > ws_size)
        split >>= 1;
    float* partials = kvt + (size_t)NH * ROWSZ;
    const int schunk = S_S / split;

    la_phase1<<<NH * split, 256, 0, stream>>>(K, V, partials, split, schunk);

    const int red_blocks = (NH * ROWSZ + 255) / 256;   // 1040 exactly
    la_reduce<<<red_blocks, 256, 0, stream>>>(partials, kvt, split);

    la_phase2<<<NH * (L_L / 256), 256, 0, stream>>>(Q, kvt, out);
}

// Round 5
// 131.507 us; speedup vs baseline: 2.1789x; 1.1377x over previous
//
#include <hip/hip_runtime.h>
#include <hip/hip_bf16.h>
#include <cstddef>
#include <cstdint>

// Problem constants (fixed by the reference setup)
#define N_B   8
#define L_L   4096
#define S_S   4096
#define H_H   8
#define D_D   64
#define NH    64          // N_B * H_H
#define COLS  65          // Dv + 1 (col 64 = K_sum)
#define ROWSZ 4160        // COLS * 64, floats per (n,h) KV_aug matrix

__device__ __forceinline__ float elu1(float x) {
    // elu(x)+1 : x>0 ? x+1 : exp(x)
    return x > 0.f ? x + 1.f : __expf(x);
}

// ---------------------------------------------------------------------------
// Phase 1: per (n,h, s-chunk) block computes partial KV_aug[65][64]
//   KV[d][v] = sum_s Kf[s][d] * V[s][v],   row 64 = K_sum[d]
// 4 waves split the s-range; each lane owns an 8x8 register tile of the 64x64
// output. No atomics: cross-wave reduce in LDS, partial written to d_ws.
// ---------------------------------------------------------------------------
__global__ __launch_bounds__(256, 4)
void la_phase1(const float* __restrict__ Kin, const float* __restrict__ Vin,
               float* __restrict__ partials, int split, int schunk)
{
    __shared__ float sK[32 * 64];        // 8 KB
    __shared__ float sV[32 * 64];        // 8 KB
    __shared__ float sAcc[64 * 68];      // 17 KB, stride 68 to dodge conflicts
    __shared__ float sKsumP[4 * 64];     // per-wave ksum partials

    const int b     = blockIdx.x;
    const int nh    = b / split;
    const int chunk = b - nh * split;
    const int n     = nh >> 3;
    const int h     = nh & 7;
    const int s0    = chunk * schunk;

    const int tid  = threadIdx.x;
    const int w    = tid >> 6;
    const int lane = tid & 63;
    const int dg   = lane >> 3;   // d-group: d = dg*8 + i
    const int vg   = lane & 7;    // v-group: v = vg*8 + j

    float acc[8][8];
    #pragma unroll
    for (int i = 0; i < 8; ++i)
        #pragma unroll
        for (int j = 0; j < 8; ++j) acc[i][j] = 0.f;
    float ksum = 0.f;

    // staging map: 256 threads cover 32 rows x 64 cols, 8 floats each
    const int sr = tid >> 3;          // 0..31
    const int sc = (tid & 7) * 8;     // 0,8,...,56
    const int kd = lane;              // ksum d index (per-wave full coverage)

    const float* Kb = Kin + (size_t)n * S_S * (H_H * D_D) + h * D_D;
    const float* Vb = Vin + (size_t)n * S_S * (H_H * D_D) + h * D_D;

    const int ntiles = schunk >> 5;   // tiles of 32 s-rows
    for (int t = 0; t < ntiles; ++t) {
        const int srow = s0 + t * 32;
        {
            const float* kg = Kb + (size_t)(srow + sr) * (H_H * D_D) + sc;
            const float* vgp = Vb + (size_t)(srow + sr) * (H_H * D_D) + sc;
            float4 ka = *(const float4*)kg;
            float4 kb = *(const float4*)(kg + 4);
            float4 va = *(const float4*)vgp;
            float4 vb = *(const float4*)(vgp + 4);
            ka.x = elu1(ka.x); ka.y = elu1(ka.y); ka.z = elu1(ka.z); ka.w = elu1(ka.w);
            kb.x = elu1(kb.x); kb.y = elu1(kb.y); kb.z = elu1(kb.z); kb.w = elu1(kb.w);
            *(float4*)&sK[sr * 64 + sc]     = ka;
            *(float4*)&sK[sr * 64 + sc + 4] = kb;
            *(float4*)&sV[sr * 64 + sc]     = va;
            *(float4*)&sV[sr * 64 + sc + 4] = vb;
        }
        __syncthreads();

        // wave w handles s-local rows w*8 .. w*8+7
        #pragma unroll
        for (int sl = 0; sl < 8; ++sl) {
            const int s = w * 8 + sl;
            const float4 k0 = *(const float4*)&sK[s * 64 + dg * 8];
            const float4 k1 = *(const float4*)&sK[s * 64 + dg * 8 + 4];
            const float4 v0 = *(const float4*)&sV[s * 64 + vg * 8];
            const float4 v1 = *(const float4*)&sV[s * 64 + vg * 8 + 4];
            const float kf[8] = {k0.x, k0.y, k0.z, k0.w, k1.x, k1.y, k1.z, k1.w};
            const float vf[8] = {v0.x, v0.y, v0.z, v0.w, v1.x, v1.y, v1.z, v1.w};
            #pragma unroll
            for (int i = 0; i < 8; ++i)
                #pragma unroll
                for (int j = 0; j < 8; ++j)
                    acc[i][j] = fmaf(kf[i], vf[j], acc[i][j]);
        }
        // K_sum partial over the same 8 rows this wave consumed
        #pragma unroll
        for (int sl = 0; sl < 8; ++sl)
            ksum += sK[(w * 8 + sl) * 64 + kd];
        __syncthreads();
    }

    // cross-wave reduce of acc into sAcc[d][v] (stride 68), sequential & exact
    for (int ww = 0; ww < 4; ++ww) {
        if (w == ww) {
            #pragma unroll
            for (int i = 0; i < 8; ++i) {
                float* p = &sAcc[(dg * 8 + i) * 68 + vg * 8];
                if (ww == 0) {
                    *(float4*)p       = make_float4(acc[i][0], acc[i][1], acc[i][2], acc[i][3]);
                    *(float4*)(p + 4) = make_float4(acc[i][4], acc[i][5], acc[i][6], acc[i][7]);
                } else {
                    float4 a0 = *(const float4*)p;
                    float4 a1 = *(const float4*)(p + 4);
                    a0.x += acc[i][0]; a0.y += acc[i][1]; a0.z += acc[i][2]; a0.w += acc[i][3];
                    a1.x += acc[i][4]; a1.y += acc[i][5]; a1.z += acc[i][6]; a1.w += acc[i][7];
                    *(float4*)p       = a0;
                    *(float4*)(p + 4) = a1;
                }
            }
        }
        __syncthreads();
    }

    // ksum: deterministic 4-way reduce (one slot per (wave, d))
    sKsumP[w * 64 + kd] = ksum;
    __syncthreads();

    // write this block's partial KV_aug in [v][d] layout (v=64 row = K_sum)
    float* outp = partials + (size_t)b * ROWSZ;
    for (int idx = tid; idx < ROWSZ; idx += 256) {
        const int v = idx >> 6;
        const int d = idx & 63;
        float val;
        if (v == 64)
            val = sKsumP[d] + sKsumP[64 + d] + sKsumP[128 + d] + sKsumP[192 + d];
        else
            val = sAcc[d * 68 + v];
        outp[idx] = val;
    }
}

// ---------------------------------------------------------------------------
// Reduce: sum the `split` partials per (n,h) -> kvt[nh][65][64]
// ---------------------------------------------------------------------------
__global__ __launch_bounds__(256)
void la_reduce(const float* __restrict__ partials, float* __restrict__ kvt, int split)
{
    const int idx = blockIdx.x * 256 + threadIdx.x;
    if (idx >= NH * ROWSZ) return;
    const int nh  = idx / ROWSZ;
    const int rem = idx - nh * ROWSZ;
    const float* p = partials + (size_t)nh * split * ROWSZ + rem;
    float s = 0.f;
    for (int c = 0; c < split; ++c) s += p[(size_t)c * ROWSZ];
    kvt[idx] = s;
}

// ---------------------------------------------------------------------------
// Phase 2 (v4): thread-per-row, 256 rows/block for fixed (n,h).
//  v3 result: spill fixed (FETCH 320->41MB) but dur stuck at 110us with
//  HBM 7% / VALU 17% / Occ 21% -> latency-bound on 1024 wave-uniform
//  global_load_dwordx4 of KV per thread (~200cy L2 round trips, not enough
//  waves to hide).
//  v4: stage KV_aug (16.6KB) in LDS once per block; the 1024 uniform loads
//  become ds_read_b128 broadcasts (conflict-free, ~5-12cy, overlap VALU).
//  Everything else unchanged from v3 (q[] in VGPRs, swizzled Q/out staging).
// ---------------------------------------------------------------------------
__global__ __launch_bounds__(256, 2)
void la_phase2(const float* __restrict__ Qin, const float* __restrict__ kvt,
               float* __restrict__ Out)
{
    __shared__ float sbuf[128 * 64];   // 32 KB, reused (Q halves, then out)
    __shared__ float sKV[ROWSZ];       // 16.6 KB, KV_aug for this (n,h)

    const int b   = blockIdx.x;
    const int nh  = b >> 4;            // 16 l-chunks per (n,h)
    const int lc  = b & 15;
    const int n   = nh >> 3;
    const int h   = nh & 7;
    const int tid = threadIdx.x;

    const float* Qc = Qin + (((size_t)n * L_L + (size_t)lc * 256) * H_H + h) * D_D;
    float*       Oc = Out + (((size_t)n * L_L + (size_t)lc * 256) * H_H + h) * D_D;

    // ---- stage KV_aug into LDS (1040 float4, coalesced) ----
    {
        const float4* src = (const float4*)(kvt + (size_t)nh * ROWSZ);
        float4*       dst = (float4*)sKV;
        #pragma unroll
        for (int it = 0; it < 4; ++it)
            dst[it * 256 + tid] = src[it * 256 + tid];
        if (tid < 16) dst[1024 + tid] = src[1024 + tid];
    }

    // staging map: slot covers 128 rows x 16 float4
    const int strow = tid >> 4;        // +it*16
    const int stc4  = tid & 15;

    float q[64];

    // ---- half 0: rows 0..127 ----
    #pragma unroll
    for (int it = 0; it < 8; ++it) {
        const int r  = it * 16 + strow;
        const int c4 = stc4 ^ (r & 7);          // XOR swizzle (float4 units)
        float4 v = *(const float4*)(Qc + (size_t)r * (H_H * D_D) + stc4 * 4);
        v.x = elu1(v.x); v.y = elu1(v.y); v.z = elu1(v.z); v.w = elu1(v.w);
        *(float4*)&sbuf[r * 64 + c4 * 4] = v;
    }
    __syncthreads();
    if (tid < 128) {
        const int r = tid;
        #pragma unroll
        for (int j = 0; j < 16; ++j) {
            const float4 v = *(const float4*)&sbuf[r * 64 + (j ^ (r & 7)) * 4];
            q[j * 4 + 0] = v.x; q[j * 4 + 1] = v.y;
            q[j * 4 + 2] = v.z; q[j * 4 + 3] = v.w;
        }
    }
    __syncthreads();

    // ---- half 1: rows 128..255 ----
    #pragma unroll
    for (int it = 0; it < 8; ++it) {
        const int r  = it * 16 + strow;
        const int c4 = stc4 ^ (r & 7);
        float4 v = *(const float4*)(Qc + (size_t)(128 + r) * (H_H * D_D) + stc4 * 4);
        v.x = elu1(v.x); v.y = elu1(v.y); v.z = elu1(v.z); v.w = elu1(v.w);
        *(float4*)&sbuf[r * 64 + c4 * 4] = v;
    }
    __syncthreads();
    if (tid >= 128) {
        const int r = tid - 128;
        #pragma unroll
        for (int j = 0; j < 16; ++j) {
            const float4 v = *(const float4*)&sbuf[r * 64 + (j ^ (r & 7)) * 4];
            q[j * 4 + 0] = v.x; q[j * 4 + 1] = v.y;
            q[j * 4 + 2] = v.z; q[j * 4 + 3] = v.w;
        }
    }
    __syncthreads();   // buffer now free for out-tile; sKV also ready

    // ---- wave-uniform KV reads from LDS (broadcast, conflict-free) ----
    const float4* __restrict__ kvp = (const float4*)sKV;

    // denominator: row v=64 of KV_aug is K_sum
    float den = 0.f;
    #pragma unroll
    for (int d4 = 0; d4 < 16; ++d4) {
        const float4 kk = kvp[64 * 16 + d4];
        den = fmaf(q[d4 * 4 + 0], kk.x, den);
        den = fmaf(q[d4 * 4 + 1], kk.y, den);
        den = fmaf(q[d4 * 4 + 2], kk.z, den);
        den = fmaf(q[d4 * 4 + 3], kk.w, den);
    }
    const float rz = 1.0f / (den + 1e-6f);

    // ---- main loop: vb dynamic, d4 FULLY unrolled (q stays in VGPRs) ----
    for (int vb = 0; vb < 16; ++vb) {
        float a0 = 0.f, a1 = 0.f, a2 = 0.f, a3 = 0.f;
        #pragma unroll
        for (int d4 = 0; d4 < 16; ++d4) {
            const float4 c0 = kvp[(vb * 4 + 0) * 16 + d4];
            const float4 c1 = kvp[(vb * 4 + 1) * 16 + d4];
            const float4 c2 = kvp[(vb * 4 + 2) * 16 + d4];
            const float4 c3 = kvp[(vb * 4 + 3) * 16 + d4];
            const float q0 = q[d4 * 4 + 0], q1 = q[d4 * 4 + 1];
            const float q2 = q[d4 * 4 + 2], q3 = q[d4 * 4 + 3];
            a0 = fmaf(q0, c0.x, a0); a0 = fmaf(q1, c0.y, a0);
            a0 = fmaf(q2, c0.z, a0); a0 = fmaf(q3, c0.w, a0);
            a1 = fmaf(q0, c1.x, a1); a1 = fmaf(q1, c1.y, a1);
            a1 = fmaf(q2, c1.z, a1); a1 = fmaf(q3, c1.w, a1);
            a2 = fmaf(q0, c2.x, a2); a2 = fmaf(q1, c2.y, a2);
            a2 = fmaf(q2, c2.z, a2); a2 = fmaf(q3, c2.w, a2);
            a3 = fmaf(q0, c3.x, a3); a3 = fmaf(q1, c3.y, a3);
            a3 = fmaf(q2, c3.z, a3); a3 = fmaf(q3, c3.w, a3);
        }
        // out-tile: row = tid (stride 32), XOR-swizzled float4 col
        *(float4*)&sbuf[tid * 32 + (((vb & 7)) ^ (tid & 7)) * 4] =
            make_float4(a0 * rz, a1 * rz, a2 * rz, a3 * rz);

        if ((vb & 7) == 7) {           // flush half the v-range, coalesced
            __syncthreads();
            const int vh = vb >> 3;    // 0 or 1
            #pragma unroll
            for (int it = 0; it < 8; ++it) {
                const int slot = it * 256 + tid;   // 0..2047
                const int r    = slot >> 3;        // 0..255
                const int c8   = slot & 7;
                const float4 v = *(const float4*)&sbuf[r * 32 + (c8 ^ (r & 7)) * 4];
                *(float4*)(Oc + (size_t)r * (H_H * D_D) + vh * 32 + c8 * 4) = v;
            }
            __syncthreads();
        }
    }
}

// ---------------------------------------------------------------------------
extern "C" void kernel_launch(void* const* d_in, const int* in_sizes, int n_in,
                              void* d_out, int out_size, void* d_ws, size_t ws_size,
                              hipStream_t stream)
{
    const float* Q = (const float*)d_in[0];
    const float* K = (const float*)d_in[1];
    const float* V = (const float*)d_in[2];
    float* out = (float*)d_out;

    // ws layout: [ kvt: NH*ROWSZ floats ][ partials: NH*split*ROWSZ floats ]
    float* kvt = (float*)d_ws;
    const size_t kvt_bytes = (size_t)NH * ROWSZ * sizeof(float);

    int split = 16;
    while (split > 1 &&
           kvt_bytes + (size_t)NH * split * ROWSZ * sizeof(float) > ws_size)
        split >>= 1;
    float* partials = kvt + (size_t)NH * ROWSZ;
    const int schunk = S_S / split;

    la_phase1<<<NH * split, 256, 0, stream>>>(K, V, partials, split, schunk);

    const int red_blocks = (NH * ROWSZ + 255) / 256;   // 1040 exactly
    la_reduce<<<red_blocks, 256, 0, stream>>>(partials, kvt, split);

    la_phase2<<<NH * (L_L / 256), 256, 0, stream>>>(Q, kvt, out);
}

// Round 6
// 99.159 us; speedup vs baseline: 2.8897x; 1.3262x over previous
//
#include <hip/hip_runtime.h>
#include <hip/hip_bf16.h>
#include <cstddef>
#include <cstdint>

// Problem constants (fixed by the reference setup)
#define N_B   8
#define L_L   4096
#define S_S   4096
#define H_H   8
#define D_D   64
#define NH    64          // N_B * H_H
// KV_aug layout (d-major): rows 0..63 = KV[d][v] (stride 68, cols 64..67 pad),
// row 64 = K_sum[d] (indexed by d in cols 0..63). KVSZ floats per (n,h).
#define KVLD  68
#define KVSZ  (65 * KVLD)   // 4420

__device__ __forceinline__ float elu1(float x) {
    // elu(x)+1 : x>0 ? x+1 : exp(x)
    return x > 0.f ? x + 1.f : __expf(x);
}

// ---------------------------------------------------------------------------
// Phase 1: per (n,h, s-chunk) block computes partial KV_aug[65][68] (d-major)
//   KV[d][v] = sum_s Kf[s][d] * V[s][v],   row 64 = K_sum[d]
// 4 waves split the s-range; each lane owns an 8x8 register tile of the 64x64
// output. No atomics: cross-wave reduce in LDS, partial written to d_ws.
// ---------------------------------------------------------------------------
__global__ __launch_bounds__(256, 4)
void la_phase1(const float* __restrict__ Kin, const float* __restrict__ Vin,
               float* __restrict__ partials, int split, int schunk)
{
    __shared__ float sK[32 * 64];        // 8 KB
    __shared__ float sV[32 * 64];        // 8 KB
    __shared__ float sAcc[64 * 68];      // 17 KB, [d][v] stride 68
    __shared__ float sKsumP[4 * 64];     // per-wave ksum partials

    const int b     = blockIdx.x;
    const int nh    = b / split;
    const int chunk = b - nh * split;
    const int n     = nh >> 3;
    const int h     = nh & 7;
    const int s0    = chunk * schunk;

    const int tid  = threadIdx.x;
    const int w    = tid >> 6;
    const int lane = tid & 63;
    const int dg   = lane >> 3;   // d-group: d = dg*8 + i
    const int vg   = lane & 7;    // v-group: v = vg*8 + j

    float acc[8][8];
    #pragma unroll
    for (int i = 0; i < 8; ++i)
        #pragma unroll
        for (int j = 0; j < 8; ++j) acc[i][j] = 0.f;
    float ksum = 0.f;

    // staging map: 256 threads cover 32 rows x 64 cols, 8 floats each
    const int sr = tid >> 3;          // 0..31
    const int sc = (tid & 7) * 8;     // 0,8,...,56
    const int kd = lane;              // ksum d index (per-wave full coverage)

    const float* Kb = Kin + (size_t)n * S_S * (H_H * D_D) + h * D_D;
    const float* Vb = Vin + (size_t)n * S_S * (H_H * D_D) + h * D_D;

    const int ntiles = schunk >> 5;   // tiles of 32 s-rows
    for (int t = 0; t < ntiles; ++t) {
        const int srow = s0 + t * 32;
        {
            const float* kg = Kb + (size_t)(srow + sr) * (H_H * D_D) + sc;
            const float* vgp = Vb + (size_t)(srow + sr) * (H_H * D_D) + sc;
            float4 ka = *(const float4*)kg;
            float4 kb = *(const float4*)(kg + 4);
            float4 va = *(const float4*)vgp;
            float4 vb = *(const float4*)(vgp + 4);
            ka.x = elu1(ka.x); ka.y = elu1(ka.y); ka.z = elu1(ka.z); ka.w = elu1(ka.w);
            kb.x = elu1(kb.x); kb.y = elu1(kb.y); kb.z = elu1(kb.z); kb.w = elu1(kb.w);
            *(float4*)&sK[sr * 64 + sc]     = ka;
            *(float4*)&sK[sr * 64 + sc + 4] = kb;
            *(float4*)&sV[sr * 64 + sc]     = va;
            *(float4*)&sV[sr * 64 + sc + 4] = vb;
        }
        __syncthreads();

        // wave w handles s-local rows w*8 .. w*8+7
        #pragma unroll
        for (int sl = 0; sl < 8; ++sl) {
            const int s = w * 8 + sl;
            const float4 k0 = *(const float4*)&sK[s * 64 + dg * 8];
            const float4 k1 = *(const float4*)&sK[s * 64 + dg * 8 + 4];
            const float4 v0 = *(const float4*)&sV[s * 64 + vg * 8];
            const float4 v1 = *(const float4*)&sV[s * 64 + vg * 8 + 4];
            const float kf[8] = {k0.x, k0.y, k0.z, k0.w, k1.x, k1.y, k1.z, k1.w};
            const float vf[8] = {v0.x, v0.y, v0.z, v0.w, v1.x, v1.y, v1.z, v1.w};
            #pragma unroll
            for (int i = 0; i < 8; ++i)
                #pragma unroll
                for (int j = 0; j < 8; ++j)
                    acc[i][j] = fmaf(kf[i], vf[j], acc[i][j]);
        }
        // K_sum partial over the same 8 rows this wave consumed
        #pragma unroll
        for (int sl = 0; sl < 8; ++sl)
            ksum += sK[(w * 8 + sl) * 64 + kd];
        __syncthreads();
    }

    // cross-wave reduce of acc into sAcc[d][v] (stride 68), sequential & exact
    for (int ww = 0; ww < 4; ++ww) {
        if (w == ww) {
            #pragma unroll
            for (int i = 0; i < 8; ++i) {
                float* p = &sAcc[(dg * 8 + i) * 68 + vg * 8];
                if (ww == 0) {
                    *(float4*)p       = make_float4(acc[i][0], acc[i][1], acc[i][2], acc[i][3]);
                    *(float4*)(p + 4) = make_float4(acc[i][4], acc[i][5], acc[i][6], acc[i][7]);
                } else {
                    float4 a0 = *(const float4*)p;
                    float4 a1 = *(const float4*)(p + 4);
                    a0.x += acc[i][0]; a0.y += acc[i][1]; a0.z += acc[i][2]; a0.w += acc[i][3];
                    a1.x += acc[i][4]; a1.y += acc[i][5]; a1.z += acc[i][6]; a1.w += acc[i][7];
                    *(float4*)p       = a0;
                    *(float4*)(p + 4) = a1;
                }
            }
        }
        __syncthreads();
    }

    // ksum: deterministic 4-way reduce (one slot per (wave, d))
    sKsumP[w * 64 + kd] = ksum;
    __syncthreads();

    // write this block's partial KV_aug[65][68] d-major (row 64 = K_sum, pads 0)
    float* outp = partials + (size_t)b * KVSZ;
    for (int idx = tid; idx < KVSZ; idx += 256) {
        const int r = idx / KVLD;
        const int c = idx - r * KVLD;
        float val = 0.f;
        if (c < 64) {
            if (r < 64)
                val = sAcc[idx];   // sAcc is [d][v] stride 68 == same layout
            else
                val = sKsumP[c] + sKsumP[64 + c] + sKsumP[128 + c] + sKsumP[192 + c];
        }
        outp[idx] = val;
    }
}

// ---------------------------------------------------------------------------
// Reduce: sum the `split` partials per (n,h) -> kvt[nh][65][68]
// ---------------------------------------------------------------------------
__global__ __launch_bounds__(256)
void la_reduce(const float* __restrict__ partials, float* __restrict__ kvt, int split)
{
    const int idx = blockIdx.x * 256 + threadIdx.x;
    if (idx >= NH * KVSZ) return;
    const int nh  = idx / KVSZ;
    const int rem = idx - nh * KVSZ;
    const float* p = partials + (size_t)nh * split * KVSZ + rem;
    float s = 0.f;
    for (int c = 0; c < split; ++c) s += p[(size_t)c * KVSZ];
    kvt[idx] = s;
}

// ---------------------------------------------------------------------------
// Phase 2 (v5): register-tiled GEMM, Out[4096][65] = Qf[4096][64]*KV[64][65].
//  v4 diagnosis: per-thread structure = 1088 uniform ds_read_b128/wave, LDS
//  instruction pipe bound (~72us arithmetic ~= 99us observed), zero register
//  reuse of KV. v5: per wave 64 rows x 32 cols, lane owns 8x4 tile
//  (rows lane&7+8j -> 8 distinct Q addrs partition all 32 banks: conflict-
//  free; cols (lane>>3)*4 -> KV reads conflict-free). Per k-chunk(4): 13
//  ds_read_b128 feed 160 FMAs; KV reused 8x, Q 4x in registers. Denominator
//  = KV row 64, accumulated per-lane for its own rows. Direct global stores
//  (8 rows x 128B contiguous per instr), no out staging, one barrier total.
// ---------------------------------------------------------------------------
__global__ __launch_bounds__(256, 2)
void la_phase2(const float* __restrict__ Qin, const float* __restrict__ kvt,
               float* __restrict__ Out)
{
    __shared__ float sQ[128 * 68];   // 34.8 KB, row-major, stride 68
    __shared__ float sKV[KVSZ];      // 17.3 KB, [65][68] d-major

    const int b   = blockIdx.x;
    const int nh  = b >> 5;          // 32 l-chunks of 128 rows per (n,h)
    const int lc  = b & 31;
    const int n   = nh >> 3;
    const int h   = nh & 7;
    const int tid = threadIdx.x;
    const int w    = tid >> 6;
    const int lane = tid & 63;

    const float* Qc = Qin + (((size_t)n * L_L + (size_t)lc * 128) * H_H + h) * D_D;
    float*       Oc = Out + (((size_t)n * L_L + (size_t)lc * 128) * H_H + h) * D_D;

    // ---- stage KV_aug[65][68] into LDS (1105 float4, coalesced) ----
    {
        const float4* src = (const float4*)(kvt + (size_t)nh * KVSZ);
        float4*       dst = (float4*)sKV;
        #pragma unroll
        for (int it = 0; it < 4; ++it)
            dst[it * 256 + tid] = src[it * 256 + tid];
        if (tid < 81) dst[1024 + tid] = src[1024 + tid];
    }

    // ---- stage Q tile 128 rows x 64 cols (elu applied), stride 68 ----
    #pragma unroll
    for (int it = 0; it < 8; ++it) {
        const int slot = it * 256 + tid;   // 0..2047
        const int r    = slot >> 4;        // 0..127
        const int c4   = slot & 15;
        float4 v = *(const float4*)(Qc + (size_t)r * (H_H * D_D) + c4 * 4);
        v.x = elu1(v.x); v.y = elu1(v.y); v.z = elu1(v.z); v.w = elu1(v.w);
        *(float4*)&sQ[r * 68 + c4 * 4] = v;
    }
    __syncthreads();

    // ---- wave work assignment ----
    const int rt   = (w >> 1) * 64;        // row tile: 0 or 64
    const int wc   = w & 1;                // col half: 0 or 1
    const int rl   = lane & 7;             // row lane: rows rt + rl + 8j
    const int cg   = lane >> 3;            // col group
    const int ccol = wc * 32 + cg * 4;     // this lane's 4 output cols

    float acc[8][4];
    float den[8];
    #pragma unroll
    for (int j = 0; j < 8; ++j) {
        den[j] = 0.f;
        #pragma unroll
        for (int m = 0; m < 4; ++m) acc[j][m] = 0.f;
    }

    const int qbase = rt + rl;             // + 8j, stride-68 rows

    for (int kc = 0; kc < 16; ++kc) {
        // Q fragments: 8 rows x 4 k  (conflict-free b128: banks partition)
        float4 qv[8];
        #pragma unroll
        for (int j = 0; j < 8; ++j)
            qv[j] = *(const float4*)&sQ[(qbase + 8 * j) * 68 + kc * 4];
        // KV fragments: 4 k-rows x lane's 4 cols (conflict-free)
        const float4 kv0 = *(const float4*)&sKV[(kc * 4 + 0) * KVLD + ccol];
        const float4 kv1 = *(const float4*)&sKV[(kc * 4 + 1) * KVLD + ccol];
        const float4 kv2 = *(const float4*)&sKV[(kc * 4 + 2) * KVLD + ccol];
        const float4 kv3 = *(const float4*)&sKV[(kc * 4 + 3) * KVLD + ccol];
        // K_sum fragment: wave-uniform broadcast
        const float4 ks  = *(const float4*)&sKV[64 * KVLD + kc * 4];

        #pragma unroll
        for (int j = 0; j < 8; ++j) {
            const float q0 = qv[j].x, q1 = qv[j].y, q2 = qv[j].z, q3 = qv[j].w;
            den[j] = fmaf(q0, ks.x, den[j]);
            den[j] = fmaf(q1, ks.y, den[j]);
            den[j] = fmaf(q2, ks.z, den[j]);
            den[j] = fmaf(q3, ks.w, den[j]);
            acc[j][0] = fmaf(q0, kv0.x, acc[j][0]);
            acc[j][0] = fmaf(q1, kv1.x, acc[j][0]);
            acc[j][0] = fmaf(q2, kv2.x, acc[j][0]);
            acc[j][0] = fmaf(q3, kv3.x, acc[j][0]);
            acc[j][1] = fmaf(q0, kv0.y, acc[j][1]);
            acc[j][1] = fmaf(q1, kv1.y, acc[j][1]);
            acc[j][1] = fmaf(q2, kv2.y, acc[j][1]);
            acc[j][1] = fmaf(q3, kv3.y, acc[j][1]);
            acc[j][2] = fmaf(q0, kv0.z, acc[j][2]);
            acc[j][2] = fmaf(q1, kv1.z, acc[j][2]);
            acc[j][2] = fmaf(q2, kv2.z, acc[j][2]);
            acc[j][2] = fmaf(q3, kv3.z, acc[j][2]);
            acc[j][3] = fmaf(q0, kv0.w, acc[j][3]);
            acc[j][3] = fmaf(q1, kv1.w, acc[j][3]);
            acc[j][3] = fmaf(q2, kv2.w, acc[j][3]);
            acc[j][3] = fmaf(q3, kv3.w, acc[j][3]);
        }
    }

    // ---- epilogue: scale by 1/(den+eps), direct coalesced global stores ----
    #pragma unroll
    for (int j = 0; j < 8; ++j) {
        const float rz = 1.0f / (den[j] + 1e-6f);
        *(float4*)(Oc + (size_t)(qbase + 8 * j) * (H_H * D_D) + ccol) =
            make_float4(acc[j][0] * rz, acc[j][1] * rz,
                        acc[j][2] * rz, acc[j][3] * rz);
    }
}

// ---------------------------------------------------------------------------
extern "C" void kernel_launch(void* const* d_in, const int* in_sizes, int n_in,
                              void* d_out, int out_size, void* d_ws, size_t ws_size,
                              hipStream_t stream)
{
    const float* Q = (const float*)d_in[0];
    const float* K = (const float*)d_in[1];
    const float* V = (const float*)d_in[2];
    float* out = (float*)d_out;

    // ws layout: [ kvt: NH*KVSZ floats ][ partials: NH*split*KVSZ floats ]
    float* kvt = (float*)d_ws;
    const size_t kvt_bytes = (size_t)NH * KVSZ * sizeof(float);

    int split = 16;
    while (split > 1 &&
           kvt_bytes + (size_t)NH * split * KVSZ * sizeof(float) > ws_size)
        split >>= 1;
    float* partials = kvt + (size_t)NH * KVSZ;
    const int schunk = S_S / split;

    la_phase1<<<NH * split, 256, 0, stream>>>(K, V, partials, split, schunk);

    const int red_blocks = (NH * KVSZ + 255) / 256;   // 1105 exactly
    la_reduce<<<red_blocks, 256, 0, stream>>>(partials, kvt, split);

    la_phase2<<<NH * (L_L / 128), 256, 0, stream>>>(Q, kvt, out);
}